// Round 15
// baseline (142.929 us; speedup 1.0000x reference)
//
#include <hip/hip_runtime.h>

#define SS 1024
#define DD 512
#define BATCH 8
#define MIN_T 0.1f
#define MAX_T 0.9f

using half4  = __attribute__((ext_vector_type(4))) _Float16;
using half8  = __attribute__((ext_vector_type(8))) _Float16;
using floatx4 = __attribute__((ext_vector_type(4))) float;

typedef const __attribute__((address_space(1))) void gvoid;
typedef __attribute__((address_space(3))) void lvoid;

// ---------------- mega prep: one dispatch, three task classes ----------------
// blocks [0,2048): adj prune+cast natural & transposed + fp32 row/col partial sums
// blocks [2048,3072): x0 cast natural + transposed
// blocks [3072,3472): Wcat transposes (z 0-3), UT transpose + Ubias/bcat pack (z 4)
__global__ void mega_k(const float* __restrict__ x0, const float* __restrict__ adj,
                       const float* __restrict__ W1, const float* __restrict__ W2,
                       const float* __restrict__ U, const float* __restrict__ b1,
                       const float* __restrict__ b2,
                       _Float16* __restrict__ adjcat, _Float16* __restrict__ x0h,
                       _Float16* __restrict__ x0t, _Float16* __restrict__ Wcat,
                       _Float16* __restrict__ UT, float* __restrict__ Ubias,
                       float* __restrict__ bcat, float* __restrict__ part) {
    __shared__ float lt[64][68];    // fp32 tile, transposed layout lt[col][row]
    __shared__ float csum[16][68];  // per-row-group column partials
    const int id = blockIdx.x;
    const int tx = threadIdx.x, ty = threadIdx.y;  // 64 x 4
    const int tid = ty * 64 + tx;
    const int i16 = tid & 15;        // 16 threads per row, 4 cols each
    const int g = tid >> 4;          // row-group 0..15

    if (id < 2048) {
        int z = id >> 8, y = (id >> 4) & 15, x = id & 15;
        int r0 = y * 64, c0 = x * 64;
        const float* src = adj + (size_t)z * SS * SS;
        _Float16* dN = adjcat + (size_t)z * SS * SS;
        _Float16* dT = adjcat + (size_t)(8 + z) * SS * SS;
        const int c4 = i16 * 4;
        float colacc[4] = {};
#pragma unroll
        for (int p = 0; p < 4; ++p) {
            int r = p * 16 + g;
            floatx4 v = *(const floatx4*)&src[(size_t)(r0 + r) * SS + c0 + c4];
#pragma unroll
            for (int j = 0; j < 4; ++j) {
                float f = v[j];
                v[j] = (f >= MIN_T && f <= MAX_T) ? f : 0.f;
                colacc[j] += v[j];
            }
            half4 h = {(_Float16)v[0], (_Float16)v[1], (_Float16)v[2], (_Float16)v[3]};
            *(half4*)&dN[(size_t)(r0 + r) * SS + c0 + c4] = h;
            lt[c4][r] = v[0]; lt[c4 + 1][r] = v[1]; lt[c4 + 2][r] = v[2]; lt[c4 + 3][r] = v[3];
            float rs = v[0] + v[1] + v[2] + v[3];
#pragma unroll
            for (int m = 8; m > 0; m >>= 1) rs += __shfl_xor(rs, m, 16);
            if (i16 == 0) part[((size_t)z * SS + r0 + r) * 16 + x] = rs;
        }
        *(floatx4*)&csum[g][c4] = *(floatx4*)colacc;
        __syncthreads();
#pragma unroll
        for (int p = 0; p < 4; ++p) {
            int cc = p * 16 + g;
            int rr = c4;
            floatx4 v = *(const floatx4*)&lt[cc][rr];
            half4 h = {(_Float16)v[0], (_Float16)v[1], (_Float16)v[2], (_Float16)v[3]};
            *(half4*)&dT[(size_t)(c0 + cc) * SS + r0 + rr] = h;
        }
        if (ty == 0) {
            float cs = 0.f;
#pragma unroll
            for (int q = 0; q < 16; ++q) cs += csum[q][tx];
            part[(size_t)131072 + ((size_t)z * SS + c0 + tx) * 16 + y] = cs;
        }
    } else if (id < 3072) {
        int rel = id - 2048;
        int z = rel >> 7, y = (rel >> 3) & 15, x = rel & 7;
        int r0 = y * 64, c0 = x * 64;
        const float* src = x0 + (size_t)z * SS * DD;
        _Float16* dN = x0h + (size_t)z * SS * DD;
        _Float16* dT = x0t + (size_t)z * SS * DD;
        const int c4 = i16 * 4;
#pragma unroll
        for (int p = 0; p < 4; ++p) {
            int r = p * 16 + g;
            floatx4 v = *(const floatx4*)&src[(size_t)(r0 + r) * DD + c0 + c4];
            half4 h = {(_Float16)v[0], (_Float16)v[1], (_Float16)v[2], (_Float16)v[3]};
            *(half4*)&dN[(size_t)(r0 + r) * DD + c0 + c4] = h;
            lt[c4][r] = v[0]; lt[c4 + 1][r] = v[1]; lt[c4 + 2][r] = v[2]; lt[c4 + 3][r] = v[3];
        }
        __syncthreads();
#pragma unroll
        for (int p = 0; p < 4; ++p) {
            int cc = p * 16 + g;
            int rr = c4;
            floatx4 v = *(const floatx4*)&lt[cc][rr];
            half4 h = {(_Float16)v[0], (_Float16)v[1], (_Float16)v[2], (_Float16)v[3]};
            *(half4*)&dT[(size_t)(c0 + cc) * SS + r0 + rr] = h;
        }
    } else {
        int rel = id - 3072;
        int z = rel / 80, rem = rel % 80;
        int y = rem / 10, x = rem % 10;
        const float* src;
        _Float16* dT;
        int sld, srcR, srcC, dTR, dTC, ldT;
        if (z < 4) {
            int l = z >> 1, st = z & 1;
            src = (st ? W2 : W1) + (size_t)l * DD * DD;
            sld = DD; srcR = DD; srcC = DD;
            dT = Wcat + (size_t)z * DD * DD; ldT = DD; dTR = DD; dTC = DD;
        } else {
            src = U; sld = 513; srcR = 512; srcC = 513;
            dT = UT; ldT = DD; dTR = 640; dTC = DD;
        }
        int c0 = x * 64, r0 = y * 64;
#pragma unroll
        for (int it = 0; it < 16; ++it) {
            int r = r0 + ty + it * 4, c = c0 + tx;
            float v = 0.f;
            if (r < srcR && c < srcC) v = src[(size_t)r * sld + c];
            lt[tx][ty + it * 4] = v;
        }
        __syncthreads();
#pragma unroll
        for (int it = 0; it < 16; ++it) {
            int tr = c0 + ty + it * 4, tc = r0 + tx;
            if (tr < dTR && tc < dTC)
                dT[(size_t)tr * ldT + tc] = (_Float16)lt[ty + it * 4][tx];
        }
        if (z == 4 && x == 0 && y == 0) {
            for (int i = tid; i < 2048; i += 256) {
                int l = i >> 10, st = (i >> 9) & 1, n = i & 511;
                bcat[i] = (st == 0) ? b1[l * 512 + n] : b2[l * 512 + n];
            }
            for (int i = tid; i < 576; i += 256) Ubias[i] = (i < 513) ? U[512 * 513 + i] : 0.f;
        }
    }
}

// ---------------- MFMA GEMM: C = A[M][K] * B[N][K]^T, fp16 in / fp32 acc ----------------
// 128x128 tile, 512 threads = 8 waves (2x4), 64x32 per wave. BK=64, double-buffered
// (validated structure; BK=32 variants measured NEGATIVE in rounds 11 & 13).
// XCD-chunked block swizzle (grid %8==0). z-batch: A += z*bA, B += (z&zmB)*bB, C += z*bC.
// EPI: 1 = agg + fp16X add; 6 = EPI1 + folded rsum (part=Cv2 -> e2, 32 rows per block);
//      2 = wmm relu((acc+bias[n])*rden[m]); 5 = EPI2 + LDS-transposed COALESCED u3 store
//      to Cv2; 3 = t1 acc+e0f[n], guard n<N; 4 = score acc+(float)e0h[m*e0ld] (C fp32)
constexpr int GBM = 128, GBN = 128, GBK = 64;

template <int EPI>
__global__ __launch_bounds__(512, 4) void gemm_k(
    const _Float16* __restrict__ A, const _Float16* __restrict__ B, void* __restrict__ Cv,
    void* __restrict__ Cv2,
    int M, int N, int K, int lda, int ldb, int ldc,
    long bA, long bB, long bC, int zmB,
    const void* __restrict__ e0, int e0ld, long bE0, int zmE,
    const float* __restrict__ e1, float* __restrict__ e2) {
    __shared__ _Float16 lA[2][GBM * GBK];  // [128][64], 8x16B chunks/row, source-swizzled
    __shared__ _Float16 lB[2][GBN * GBK];  // [128][64]

    const int gx = gridDim.x, gy = gridDim.y;
    const int nwg = gx * gy * gridDim.z;
    const int orig = (blockIdx.z * gy + blockIdx.y) * gx + blockIdx.x;
    const int w = (orig & 7) * (nwg >> 3) + (orig >> 3);
    const int bx = w % gx;
    const int wt = w / gx;
    const int by = wt % gy;
    const int z = wt / gy;

    A += (size_t)z * bA;
    B += (size_t)(z & zmB) * bB;
    const int m0 = bx * GBM, n0 = by * GBN;
    const int tid = threadIdx.x;
    const int lane = tid & 63, wv = tid >> 6;
    const int wr = wv >> 2, wc = wv & 3;  // 2x4 waves, 64x32 per wave

    auto stage = [&](int buf, int kt) {
#pragma unroll
        for (int it = 0; it < 2; ++it) {  // A: 1024 chunks
            int q = it * 512 + tid;
            int r = q >> 3, cp = q & 7, cl = cp ^ (r & 7);
            const _Float16* g = A + (size_t)(m0 + r) * lda + kt + cl * 8;
            __builtin_amdgcn_global_load_lds((gvoid*)g,
                (lvoid*)(&lA[buf][(it * 512 + wv * 64) * 8]), 16, 0, 0);
        }
#pragma unroll
        for (int it = 0; it < 2; ++it) {  // B: 1024 chunks
            int q = it * 512 + tid;
            int r = q >> 3, cp = q & 7, cl = cp ^ (r & 7);
            const _Float16* g = B + (size_t)(n0 + r) * ldb + kt + cl * 8;
            __builtin_amdgcn_global_load_lds((gvoid*)g,
                (lvoid*)(&lB[buf][(it * 512 + wv * 64) * 8]), 16, 0, 0);
        }
    };

    floatx4 acc[4][2] = {};

    stage(0, 0);
    asm volatile("s_waitcnt vmcnt(0)");
    __syncthreads();
    int cur = 0;
    for (int kt = 0; kt < K; kt += GBK) {
        int nxt = kt + GBK;
        if (nxt < K) stage(cur ^ 1, nxt);
#pragma unroll
        for (int kk = 0; kk < 2; ++kk) {
            half8 af[4], bf[2];
#pragma unroll
            for (int i = 0; i < 4; ++i) {
                int row = wr * 64 + i * 16 + (lane & 15);
                int cl = kk * 4 + (lane >> 4);
                int cp = cl ^ (row & 7);
                af[i] = *(const half8*)&lA[cur][row * 64 + cp * 8];
            }
#pragma unroll
            for (int j = 0; j < 2; ++j) {
                int row = wc * 32 + j * 16 + (lane & 15);
                int cl = kk * 4 + (lane >> 4);
                int cp = cl ^ (row & 7);
                bf[j] = *(const half8*)&lB[cur][row * 64 + cp * 8];
            }
#pragma unroll
            for (int i = 0; i < 4; ++i)
#pragma unroll
                for (int j = 0; j < 2; ++j)
                    acc[i][j] = __builtin_amdgcn_mfma_f32_16x16x32_f16(af[i], bf[j], acc[i][j], 0, 0, 0);
        }
        if (nxt < K) {
            asm volatile("s_waitcnt vmcnt(0)");
            __syncthreads();
        }
        cur ^= 1;
    }

    // epilogue: C map col=lane&15, row=(lane>>4)*4+r
    const int cm = (lane >> 4) * 4;
    const int cn = lane & 15;
    const long bAct = (long)SS * DD;

    // EPI5: LDS transpose buffer T[n][m] (fp16, 32KB) overlaid on lA. Barrier first:
    // other waves may still be reading lA in their last K-iteration.
    _Float16* T = &lA[0][0];
    if constexpr (EPI == 5) __syncthreads();

#pragma unroll
    for (int i = 0; i < 4; ++i) {
#pragma unroll
        for (int j = 0; j < 2; ++j) {
            float vs[4];
#pragma unroll
            for (int r = 0; r < 4; ++r) {
                int m = m0 + wr * 64 + i * 16 + cm + r;
                int n = n0 + wc * 32 + j * 16 + cn;
                float v = acc[i][j][r];
                if constexpr (EPI == 1 || EPI == 6) {
                    const _Float16* X = (const _Float16*)e0 + (size_t)(z & zmE) * bE0;
                    v += (float)X[(size_t)m * e0ld + n];
                    ((_Float16*)Cv)[(size_t)z * bC + (size_t)m * ldc + n] = (_Float16)v;
                } else if constexpr (EPI == 2 || EPI == 5) {
                    const float* bb = (const float*)e0 + (size_t)(z & zmE) * bE0;
                    v = (v + bb[n]) * e1[(size_t)z * e0ld + m];
                    v = v > 0.f ? v : 0.f;
                    ((_Float16*)Cv)[(size_t)z * bC + (size_t)m * ldc + n] = (_Float16)v;
                    vs[r] = v;
                } else if constexpr (EPI == 3) {
                    if (n < N) {
                        v += ((const float*)e0)[n];
                        ((_Float16*)Cv)[(size_t)z * bC + (size_t)m * ldc + n] = (_Float16)v;
                    }
                } else {
                    const _Float16* tb = (const _Float16*)e0 + (size_t)(z & zmE) * bE0;
                    v += (float)tb[(size_t)m * e0ld];
                    ((float*)Cv)[(size_t)z * bC + (size_t)m * ldc + n] = v;
                }
            }
            if constexpr (EPI == 5) {
                // stage transposed into LDS: T row = n_loc (128 halfs), 16B-unit XOR swizzle
                int m_loc = wr * 64 + i * 16 + cm;        // multiple of 4
                int n_loc = wc * 32 + j * 16 + cn;        // 0..127
                int u = m_loc >> 3;                        // 16B unit index 0..15
                int off = (m_loc >> 2) & 1;                // half4 slot within unit
                half4 h = {(_Float16)vs[0], (_Float16)vs[1], (_Float16)vs[2], (_Float16)vs[3]};
                *(half4*)&T[n_loc * 128 + ((u ^ (n_loc & 15)) << 3) + off * 4] = h;
            }
        }
    }
    if constexpr (EPI == 5) {
        __syncthreads();
        // coalesced u3 store: thread t -> u3 row n_loc = t>>2, 32-m chunk = (t&3)*32 (64B)
        int n_loc = tid >> 2;
        int mc = (tid & 3) * 32;
        int bt = m0 >> 10;                   // tile never straddles a batch (1024%128==0)
        int s = (m0 & 1023) + mc;
        _Float16* dst = (_Float16*)Cv2 + (size_t)(z * 8 + bt) * bAct +
                        (size_t)(n0 + n_loc) * SS + s;
#pragma unroll
        for (int k = 0; k < 4; ++k) {
            int u = (mc >> 3) + k;
            half8 h8 = *(const half8*)&T[n_loc * 128 + ((u ^ (n_loc & 15)) << 3)];
            *(half8*)&dst[k * 8] = h8;
        }
    }
    if constexpr (EPI == 6) {
        // folded denominator reduce: this block handles part rows [w*32, w*32+32)
        const float* part = (const float*)Cv2;
        int row = w * 32 + (tid >> 4);
        float s = part[(size_t)row * 16 + (tid & 15)];
        s += __shfl_xor(s, 1, 16);
        s += __shfl_xor(s, 2, 16);
        s += __shfl_xor(s, 4, 16);
        s += __shfl_xor(s, 8, 16);
        if ((tid & 15) == 0) e2[row] = 1.0f / (s + 1.0f);
    }
}

extern "C" void kernel_launch(void* const* d_in, const int* in_sizes, int n_in,
                              void* d_out, int out_size, void* d_ws, size_t ws_size,
                              hipStream_t stream) {
    const float* x0  = (const float*)d_in[0];  // [B,S,D]
    const float* adj = (const float*)d_in[1];  // [B,S,S]
    const float* W1  = (const float*)d_in[2];  // [L,D,D]
    const float* b1  = (const float*)d_in[3];  // [L,D]
    const float* W2  = (const float*)d_in[4];
    const float* b2  = (const float*)d_in[5];
    const float* U   = (const float*)d_in[6];  // [1,513,513]
    float* out = (float*)d_out;

    char* ws = (char*)d_ws;
    const size_t MB = 1u << 20;
    const long bAdj = (long)SS * SS, bAct = (long)SS * DD;
    const long DD2 = (long)DD * DD;
    _Float16* adjcat = (_Float16*)(ws);            // 32 MB: 16 mats (8 natural, 8 transposed)
    _Float16* x0t  = (_Float16*)(ws + 32 * MB);    // 8 MB x0^T fp16
    _Float16* x0h  = (_Float16*)(ws + 40 * MB);    // 8 MB x0 fp16 natural
    _Float16* u1   = (_Float16*)(ws + 48 * MB);    // 16 MB Y (both streams)
    _Float16* u2   = (_Float16*)(ws + 64 * MB);    // 16 MB X' natural (both streams)
    _Float16* u3   = (_Float16*)(ws + 80 * MB);    // 16 MB X'^T (both streams)
    _Float16* h12  = (_Float16*)(ws + 96 * MB);    // 16 MB h1 (z 0-7) + h2 (z 8-15)
    _Float16* t1h  = (_Float16*)(ws + 112 * MB);   // [8192][576] 9.44 MB
    _Float16* Wcat = (_Float16*)(ws + 122 * MB);   // [2 layer][2 stream][512][512] = 2 MB (122-124)
    _Float16* UT   = (_Float16*)(ws + 124 * MB);   // [640][512] zero-padded, 0.64 MB
    float* Ubias   = (float*)(ws + 125 * MB);          // [576]
    float* bcat    = (float*)(ws + 125 * MB + 4096);   // [2][2][512]
    float* rden12  = (float*)(ws + 125 * MB + 16384);  // [16384] (64 KB)
    float* part    = (float*)(ws + 126 * MB);          // [16384][16] = 1 MB

    // one mega prep dispatch: adj (2048 blocks) + x0 (1024) + weights/U/bias (400)
    mega_k<<<3472, dim3(64, 4), 0, stream>>>(x0, adj, W1, W2, U, b1, b2,
                                             adjcat, x0h, x0t, Wcat, UT, Ubias, bcat, part);

    dim3 gAgg(SS / GBM, DD / GBN, 16);           // 512 blocks, 2/CU
    dim3 gWmm(BATCH * SS / GBM, DD / GBN, 2);    // 512 blocks (both streams)
    dim3 gT1(BATCH * SS / GBM, 5, 1);            // 320 blocks, N padded to 640
    dim3 gSc(SS / GBM, SS / GBN, BATCH);         // 512 blocks

    // layer 0 aggregation (both streams) + folded denominator reduce (part -> rden12)
    gemm_k<6><<<gAgg, 512, 0, stream>>>(adjcat, x0t, u1, part, SS, DD, SS, SS, SS, DD,
                                        bAdj, bAct, bAct, 7, x0h, DD, bAct, 7, nullptr, rden12);
    // layer 0 transform, both streams; epilogue writes u2 + LDS-coalesced u3
    gemm_k<5><<<gWmm, 512, 0, stream>>>(u1, Wcat, u2, u3, BATCH * SS, DD, DD, DD, DD, DD,
                                        8 * bAct, DD2, 8 * bAct, 1,
                                        bcat, 8192, 512, 1, rden12, nullptr);
    // layer 1 aggregation (B = X'^T, self-loop add = X' natural)
    gemm_k<1><<<gAgg, 512, 0, stream>>>(adjcat, u3, u1, nullptr, SS, DD, SS, SS, SS, DD,
                                        bAdj, bAct, bAct, 15, u2, DD, bAct, 15, nullptr, nullptr);
    // layer 1 transform -> h1 (z=0) / h2 (z=1)
    gemm_k<2><<<gWmm, 512, 0, stream>>>(u1, Wcat + 2 * DD2, h12, nullptr,
                                        BATCH * SS, DD, DD, DD, DD, DD,
                                        8 * bAct, DD2, 8 * bAct, 1,
                                        bcat + 1024, 8192, 512, 1, rden12, nullptr);

    // t1 = [h1|1]*U
    gemm_k<3><<<gT1, 512, 0, stream>>>(h12, UT, t1h, nullptr, BATCH * SS, 576, DD, DD, DD, 576,
                                       0, 0, 0, 0, Ubias, 0, 0, 0, nullptr, nullptr);
    // score[b,x,y] = t1[b,x,:512].h2[b,y,:512] + t1[b,x,512]
    gemm_k<4><<<gSc, 512, 0, stream>>>(t1h, h12 + 8 * bAct, out, nullptr, SS, SS, DD, 576, DD, SS,
                                       (long)SS * 576, bAct, (long)SS * SS, 15,
                                       t1h + 512, 576, (long)SS * 576, 15, nullptr, nullptr);
}

// Round 17
// 140.249 us; speedup vs baseline: 1.0191x; 1.0191x over previous
//
#include <hip/hip_runtime.h>

#define SS 1024
#define DD 512
#define BATCH 8
#define MIN_T 0.1f
#define MAX_T 0.9f

using half4  = __attribute__((ext_vector_type(4))) _Float16;
using half8  = __attribute__((ext_vector_type(8))) _Float16;
using floatx4 = __attribute__((ext_vector_type(4))) float;

typedef const __attribute__((address_space(1))) void gvoid;
typedef __attribute__((address_space(3))) void lvoid;

// ---------------- mega prep: one dispatch, three task classes ----------------
// blocks [0,2048): adj prune+cast natural & transposed + fp32 row/col partial sums
// blocks [2048,3072): x0 cast natural + transposed
// blocks [3072,3472): Wcat transposes (z 0-3), UT transpose + Ubias/bcat pack (z 4)
__global__ void mega_k(const float* __restrict__ x0, const float* __restrict__ adj,
                       const float* __restrict__ W1, const float* __restrict__ W2,
                       const float* __restrict__ U, const float* __restrict__ b1,
                       const float* __restrict__ b2,
                       _Float16* __restrict__ adjcat, _Float16* __restrict__ x0h,
                       _Float16* __restrict__ x0t, _Float16* __restrict__ Wcat,
                       _Float16* __restrict__ UT, float* __restrict__ Ubias,
                       float* __restrict__ bcat, float* __restrict__ part) {
    __shared__ float lt[64][68];    // fp32 tile, transposed layout lt[col][row]
    __shared__ float csum[16][68];  // per-row-group column partials
    const int id = blockIdx.x;
    const int tx = threadIdx.x, ty = threadIdx.y;  // 64 x 4
    const int tid = ty * 64 + tx;
    const int i16 = tid & 15;        // 16 threads per row, 4 cols each
    const int g = tid >> 4;          // row-group 0..15

    if (id < 2048) {
        int z = id >> 8, y = (id >> 4) & 15, x = id & 15;
        int r0 = y * 64, c0 = x * 64;
        const float* src = adj + (size_t)z * SS * SS;
        _Float16* dN = adjcat + (size_t)z * SS * SS;
        _Float16* dT = adjcat + (size_t)(8 + z) * SS * SS;
        const int c4 = i16 * 4;
        float colacc[4] = {};
#pragma unroll
        for (int p = 0; p < 4; ++p) {
            int r = p * 16 + g;
            floatx4 v = *(const floatx4*)&src[(size_t)(r0 + r) * SS + c0 + c4];
#pragma unroll
            for (int j = 0; j < 4; ++j) {
                float f = v[j];
                v[j] = (f >= MIN_T && f <= MAX_T) ? f : 0.f;
                colacc[j] += v[j];
            }
            half4 h = {(_Float16)v[0], (_Float16)v[1], (_Float16)v[2], (_Float16)v[3]};
            *(half4*)&dN[(size_t)(r0 + r) * SS + c0 + c4] = h;
            lt[c4][r] = v[0]; lt[c4 + 1][r] = v[1]; lt[c4 + 2][r] = v[2]; lt[c4 + 3][r] = v[3];
            float rs = v[0] + v[1] + v[2] + v[3];
#pragma unroll
            for (int m = 8; m > 0; m >>= 1) rs += __shfl_xor(rs, m, 16);
            if (i16 == 0) part[((size_t)z * SS + r0 + r) * 16 + x] = rs;
        }
        *(floatx4*)&csum[g][c4] = *(floatx4*)colacc;
        __syncthreads();
#pragma unroll
        for (int p = 0; p < 4; ++p) {
            int cc = p * 16 + g;
            int rr = c4;
            floatx4 v = *(const floatx4*)&lt[cc][rr];
            half4 h = {(_Float16)v[0], (_Float16)v[1], (_Float16)v[2], (_Float16)v[3]};
            *(half4*)&dT[(size_t)(c0 + cc) * SS + r0 + rr] = h;
        }
        if (ty == 0) {
            float cs = 0.f;
#pragma unroll
            for (int q = 0; q < 16; ++q) cs += csum[q][tx];
            part[(size_t)131072 + ((size_t)z * SS + c0 + tx) * 16 + y] = cs;
        }
    } else if (id < 3072) {
        int rel = id - 2048;
        int z = rel >> 7, y = (rel >> 3) & 15, x = rel & 7;
        int r0 = y * 64, c0 = x * 64;
        const float* src = x0 + (size_t)z * SS * DD;
        _Float16* dN = x0h + (size_t)z * SS * DD;
        _Float16* dT = x0t + (size_t)z * SS * DD;
        const int c4 = i16 * 4;
#pragma unroll
        for (int p = 0; p < 4; ++p) {
            int r = p * 16 + g;
            floatx4 v = *(const floatx4*)&src[(size_t)(r0 + r) * DD + c0 + c4];
            half4 h = {(_Float16)v[0], (_Float16)v[1], (_Float16)v[2], (_Float16)v[3]};
            *(half4*)&dN[(size_t)(r0 + r) * DD + c0 + c4] = h;
            lt[c4][r] = v[0]; lt[c4 + 1][r] = v[1]; lt[c4 + 2][r] = v[2]; lt[c4 + 3][r] = v[3];
        }
        __syncthreads();
#pragma unroll
        for (int p = 0; p < 4; ++p) {
            int cc = p * 16 + g;
            int rr = c4;
            floatx4 v = *(const floatx4*)&lt[cc][rr];
            half4 h = {(_Float16)v[0], (_Float16)v[1], (_Float16)v[2], (_Float16)v[3]};
            *(half4*)&dT[(size_t)(c0 + cc) * SS + r0 + rr] = h;
        }
    } else {
        int rel = id - 3072;
        int z = rel / 80, rem = rel % 80;
        int y = rem / 10, x = rem % 10;
        const float* src;
        _Float16* dT;
        int sld, srcR, srcC, dTR, dTC, ldT;
        if (z < 4) {
            int l = z >> 1, st = z & 1;
            src = (st ? W2 : W1) + (size_t)l * DD * DD;
            sld = DD; srcR = DD; srcC = DD;
            dT = Wcat + (size_t)z * DD * DD; ldT = DD; dTR = DD; dTC = DD;
        } else {
            src = U; sld = 513; srcR = 512; srcC = 513;
            dT = UT; ldT = DD; dTR = 640; dTC = DD;
        }
        int c0 = x * 64, r0 = y * 64;
#pragma unroll
        for (int it = 0; it < 16; ++it) {
            int r = r0 + ty + it * 4, c = c0 + tx;
            float v = 0.f;
            if (r < srcR && c < srcC) v = src[(size_t)r * sld + c];
            lt[tx][ty + it * 4] = v;
        }
        __syncthreads();
#pragma unroll
        for (int it = 0; it < 16; ++it) {
            int tr = c0 + ty + it * 4, tc = r0 + tx;
            if (tr < dTR && tc < dTC)
                dT[(size_t)tr * ldT + tc] = (_Float16)lt[ty + it * 4][tx];
        }
        if (z == 4 && x == 0 && y == 0) {
            for (int i = tid; i < 2048; i += 256) {
                int l = i >> 10, st = (i >> 9) & 1, n = i & 511;
                bcat[i] = (st == 0) ? b1[l * 512 + n] : b2[l * 512 + n];
            }
            for (int i = tid; i < 576; i += 256) Ubias[i] = (i < 513) ? U[512 * 513 + i] : 0.f;
        }
    }
}

// ---------------- MFMA GEMM: C = A[M][K] * B[N][K]^T, fp16 in / fp32 acc ----------------
// 128x128 tile, 512 threads = 8 waves (2x4), 64x32 per wave. BK=64, double-buffered.
// SYNC DISCIPLINE: plain __syncthreads() only (emits s_waitcnt vmcnt(0) lgkmcnt(0) +
// s_barrier as one unit — m97-verified). The previous inline-asm "s_waitcnt vmcnt(0)"
// lacked a "memory" clobber, letting the compiler reorder global_load_lds across it:
// a staged load could land AFTER the next iteration's ds_read (flaky post-timing
// divergence, round 16). Never reintroduce un-clobbered waitcnt asm here.
// XCD-chunked block swizzle (grid %8==0). z-batch: A += z*bA, B += (z&zmB)*bB, C += z*bC.
// EPI: 1 = agg + fp16X add; 6 = EPI1 + folded rsum (part=Cv2 -> e2, 32 rows per block);
//      2 = wmm relu((acc+bias[n])*rden[m]); 5 = EPI2 + half4-vectorized transposed store
//      to Cv2; 3 = t1 acc+e0f[n], guard n<N; 4 = score acc+(float)e0h[m*e0ld] (C fp32)
constexpr int GBM = 128, GBN = 128, GBK = 64;

template <int EPI>
__global__ __launch_bounds__(512, 4) void gemm_k(
    const _Float16* __restrict__ A, const _Float16* __restrict__ B, void* __restrict__ Cv,
    void* __restrict__ Cv2,
    int M, int N, int K, int lda, int ldb, int ldc,
    long bA, long bB, long bC, int zmB,
    const void* __restrict__ e0, int e0ld, long bE0, int zmE,
    const float* __restrict__ e1, float* __restrict__ e2) {
    __shared__ _Float16 lA[2][GBM * GBK];  // [128][64], 8x16B chunks/row, source-swizzled
    __shared__ _Float16 lB[2][GBN * GBK];  // [128][64]

    const int gx = gridDim.x, gy = gridDim.y;
    const int nwg = gx * gy * gridDim.z;
    const int orig = (blockIdx.z * gy + blockIdx.y) * gx + blockIdx.x;
    const int w = (orig & 7) * (nwg >> 3) + (orig >> 3);
    const int bx = w % gx;
    const int wt = w / gx;
    const int by = wt % gy;
    const int z = wt / gy;

    A += (size_t)z * bA;
    B += (size_t)(z & zmB) * bB;
    const int m0 = bx * GBM, n0 = by * GBN;
    const int tid = threadIdx.x;
    const int lane = tid & 63, wv = tid >> 6;
    const int wr = wv >> 2, wc = wv & 3;  // 2x4 waves, 64x32 per wave

    auto stage = [&](int buf, int kt) {
#pragma unroll
        for (int it = 0; it < 2; ++it) {  // A: 1024 chunks
            int q = it * 512 + tid;
            int r = q >> 3, cp = q & 7, cl = cp ^ (r & 7);
            const _Float16* g = A + (size_t)(m0 + r) * lda + kt + cl * 8;
            __builtin_amdgcn_global_load_lds((gvoid*)g,
                (lvoid*)(&lA[buf][(it * 512 + wv * 64) * 8]), 16, 0, 0);
        }
#pragma unroll
        for (int it = 0; it < 2; ++it) {  // B: 1024 chunks
            int q = it * 512 + tid;
            int r = q >> 3, cp = q & 7, cl = cp ^ (r & 7);
            const _Float16* g = B + (size_t)(n0 + r) * ldb + kt + cl * 8;
            __builtin_amdgcn_global_load_lds((gvoid*)g,
                (lvoid*)(&lB[buf][(it * 512 + wv * 64) * 8]), 16, 0, 0);
        }
    };

    floatx4 acc[4][2] = {};

    stage(0, 0);
    __syncthreads();  // drains vmcnt(0)+lgkmcnt(0) then barriers (single unit)
    int cur = 0;
    for (int kt = 0; kt < K; kt += GBK) {
        int nxt = kt + GBK;
        if (nxt < K) stage(cur ^ 1, nxt);
#pragma unroll
        for (int kk = 0; kk < 2; ++kk) {
            half8 af[4], bf[2];
#pragma unroll
            for (int i = 0; i < 4; ++i) {
                int row = wr * 64 + i * 16 + (lane & 15);
                int cl = kk * 4 + (lane >> 4);
                int cp = cl ^ (row & 7);
                af[i] = *(const half8*)&lA[cur][row * 64 + cp * 8];
            }
#pragma unroll
            for (int j = 0; j < 2; ++j) {
                int row = wc * 32 + j * 16 + (lane & 15);
                int cl = kk * 4 + (lane >> 4);
                int cp = cl ^ (row & 7);
                bf[j] = *(const half8*)&lB[cur][row * 64 + cp * 8];
            }
#pragma unroll
            for (int i = 0; i < 4; ++i)
#pragma unroll
                for (int j = 0; j < 2; ++j)
                    acc[i][j] = __builtin_amdgcn_mfma_f32_16x16x32_f16(af[i], bf[j], acc[i][j], 0, 0, 0);
        }
        if (nxt < K) __syncthreads();  // full drain + barrier; covers in-flight stage loads
        cur ^= 1;
    }

    // epilogue: C map col=lane&15, row=(lane>>4)*4+r
    const int cm = (lane >> 4) * 4;
    const int cn = lane & 15;
    const long bAct = (long)SS * DD;
#pragma unroll
    for (int i = 0; i < 4; ++i) {
#pragma unroll
        for (int j = 0; j < 2; ++j) {
            float vs[4];
#pragma unroll
            for (int r = 0; r < 4; ++r) {
                int m = m0 + wr * 64 + i * 16 + cm + r;
                int n = n0 + wc * 32 + j * 16 + cn;
                float v = acc[i][j][r];
                if constexpr (EPI == 1 || EPI == 6) {
                    const _Float16* X = (const _Float16*)e0 + (size_t)(z & zmE) * bE0;
                    v += (float)X[(size_t)m * e0ld + n];
                    ((_Float16*)Cv)[(size_t)z * bC + (size_t)m * ldc + n] = (_Float16)v;
                } else if constexpr (EPI == 2 || EPI == 5) {
                    const float* bb = (const float*)e0 + (size_t)(z & zmE) * bE0;
                    v = (v + bb[n]) * e1[(size_t)z * e0ld + m];
                    v = v > 0.f ? v : 0.f;
                    ((_Float16*)Cv)[(size_t)z * bC + (size_t)m * ldc + n] = (_Float16)v;
                    vs[r] = v;
                } else if constexpr (EPI == 3) {
                    if (n < N) {
                        v += ((const float*)e0)[n];
                        ((_Float16*)Cv)[(size_t)z * bC + (size_t)m * ldc + n] = (_Float16)v;
                    }
                } else {
                    const _Float16* tb = (const _Float16*)e0 + (size_t)(z & zmE) * bE0;
                    v += (float)tb[(size_t)m * e0ld];
                    ((float*)Cv)[(size_t)z * bC + (size_t)m * ldc + n] = v;
                }
            }
            if constexpr (EPI == 5) {
                // transposed store: 4 consecutive m at fixed n -> one half4 (8B) store
                int mb = m0 + wr * 64 + i * 16 + cm;
                int n = n0 + wc * 32 + j * 16 + cn;
                int bt = mb >> 10, s = mb & 1023;
                half4 h = {(_Float16)vs[0], (_Float16)vs[1], (_Float16)vs[2], (_Float16)vs[3]};
                *(half4*)&((_Float16*)Cv2)[(size_t)(z * 8 + bt) * bAct + (size_t)n * SS + s] = h;
            }
        }
    }
    if constexpr (EPI == 6) {
        // folded denominator reduce: this block handles part rows [w*32, w*32+32)
        const float* part = (const float*)Cv2;
        int row = w * 32 + (tid >> 4);
        float s = part[(size_t)row * 16 + (tid & 15)];
        s += __shfl_xor(s, 1, 16);
        s += __shfl_xor(s, 2, 16);
        s += __shfl_xor(s, 4, 16);
        s += __shfl_xor(s, 8, 16);
        if ((tid & 15) == 0) e2[row] = 1.0f / (s + 1.0f);
    }
}

extern "C" void kernel_launch(void* const* d_in, const int* in_sizes, int n_in,
                              void* d_out, int out_size, void* d_ws, size_t ws_size,
                              hipStream_t stream) {
    const float* x0  = (const float*)d_in[0];  // [B,S,D]
    const float* adj = (const float*)d_in[1];  // [B,S,S]
    const float* W1  = (const float*)d_in[2];  // [L,D,D]
    const float* b1  = (const float*)d_in[3];  // [L,D]
    const float* W2  = (const float*)d_in[4];
    const float* b2  = (const float*)d_in[5];
    const float* U   = (const float*)d_in[6];  // [1,513,513]
    float* out = (float*)d_out;

    char* ws = (char*)d_ws;
    const size_t MB = 1u << 20;
    const long bAdj = (long)SS * SS, bAct = (long)SS * DD;
    const long DD2 = (long)DD * DD;
    _Float16* adjcat = (_Float16*)(ws);            // 32 MB: 16 mats (8 natural, 8 transposed)
    _Float16* x0t  = (_Float16*)(ws + 32 * MB);    // 8 MB x0^T fp16
    _Float16* x0h  = (_Float16*)(ws + 40 * MB);    // 8 MB x0 fp16 natural
    _Float16* u1   = (_Float16*)(ws + 48 * MB);    // 16 MB Y (both streams)
    _Float16* u2   = (_Float16*)(ws + 64 * MB);    // 16 MB X' natural (both streams)
    _Float16* u3   = (_Float16*)(ws + 80 * MB);    // 16 MB X'^T (both streams)
    _Float16* h12  = (_Float16*)(ws + 96 * MB);    // 16 MB h1 (z 0-7) + h2 (z 8-15)
    _Float16* t1h  = (_Float16*)(ws + 112 * MB);   // [8192][576] 9.44 MB
    _Float16* Wcat = (_Float16*)(ws + 122 * MB);   // [2 layer][2 stream][512][512] = 2 MB (122-124)
    _Float16* UT   = (_Float16*)(ws + 124 * MB);   // [640][512] zero-padded, 0.64 MB
    float* Ubias   = (float*)(ws + 125 * MB);          // [576]
    float* bcat    = (float*)(ws + 125 * MB + 4096);   // [2][2][512]
    float* rden12  = (float*)(ws + 125 * MB + 16384);  // [16384] (64 KB)
    float* part    = (float*)(ws + 126 * MB);          // [16384][16] = 1 MB

    // one mega prep dispatch: adj (2048 blocks) + x0 (1024) + weights/U/bias (400)
    mega_k<<<3472, dim3(64, 4), 0, stream>>>(x0, adj, W1, W2, U, b1, b2,
                                             adjcat, x0h, x0t, Wcat, UT, Ubias, bcat, part);

    dim3 gAgg(SS / GBM, DD / GBN, 16);           // 512 blocks, 2/CU
    dim3 gWmm(BATCH * SS / GBM, DD / GBN, 2);    // 512 blocks (both streams)
    dim3 gT1(BATCH * SS / GBM, 5, 1);            // 320 blocks, N padded to 640
    dim3 gSc(SS / GBM, SS / GBN, BATCH);         // 512 blocks

    // layer 0 aggregation (both streams) + folded denominator reduce (part -> rden12)
    gemm_k<6><<<gAgg, 512, 0, stream>>>(adjcat, x0t, u1, part, SS, DD, SS, SS, SS, DD,
                                        bAdj, bAct, bAct, 7, x0h, DD, bAct, 7, nullptr, rden12);
    // layer 0 transform, both streams; epilogue also writes X'^T -> u3 (half4 stores)
    gemm_k<5><<<gWmm, 512, 0, stream>>>(u1, Wcat, u2, u3, BATCH * SS, DD, DD, DD, DD, DD,
                                        8 * bAct, DD2, 8 * bAct, 1,
                                        bcat, 8192, 512, 1, rden12, nullptr);
    // layer 1 aggregation (B = X'^T, self-loop add = X' natural)
    gemm_k<1><<<gAgg, 512, 0, stream>>>(adjcat, u3, u1, nullptr, SS, DD, SS, SS, SS, DD,
                                        bAdj, bAct, bAct, 15, u2, DD, bAct, 15, nullptr, nullptr);
    // layer 1 transform -> h1 (z=0) / h2 (z=1)
    gemm_k<2><<<gWmm, 512, 0, stream>>>(u1, Wcat + 2 * DD2, h12, nullptr,
                                        BATCH * SS, DD, DD, DD, DD, DD,
                                        8 * bAct, DD2, 8 * bAct, 1,
                                        bcat + 1024, 8192, 512, 1, rden12, nullptr);

    // t1 = [h1|1]*U
    gemm_k<3><<<gT1, 512, 0, stream>>>(h12, UT, t1h, nullptr, BATCH * SS, 576, DD, DD, DD, 576,
                                       0, 0, 0, 0, Ubias, 0, 0, 0, nullptr, nullptr);
    // score[b,x,y] = t1[b,x,:512].h2[b,y,:512] + t1[b,x,512]
    gemm_k<4><<<gSc, 512, 0, stream>>>(t1h, h12 + 8 * bAct, out, nullptr, SS, SS, DD, 576, DD, SS,
                                       (long)SS * 576, bAct, (long)SS * SS, 15,
                                       t1h + 512, 576, (long)SS * 576, 15, nullptr, nullptr);
}